// Round 1
// baseline (272.437 us; speedup 1.0000x reference)
//
#include <hip/hip_runtime.h>

#define BB 16
#define FF 256
#define TT 8192
#define F_CHUNK 64
#define THREADS 256

__device__ __forceinline__ int sgn_bit(float x) {
    return (int)(__float_as_uint(x) >> 31);
}

__global__ __launch_bounds__(THREADS) void sst_kernel(const float* __restrict__ in,
                                                      float* __restrict__ out) {
    const int t   = blockIdx.x * (THREADS * 4) + threadIdx.x * 4;
    const int fs  = blockIdx.y * F_CHUNK;
    const int b   = blockIdx.z;
    const int lane = threadIdx.x & 63;

    const float* src = in  + (size_t)b * FF * TT + t;
    float*       dst = out + (size_t)b * FF * TT + t;

    // true only for the thread whose last element is t+3 == TT-1 (pad column)
    const bool tail = (t + 4 >= TT);

    float4 vprev, vcur, vnext;
    int4   aprev, acur, anext;

    auto load_row = [&](int f, float4& v, int4& a) {
        v = *reinterpret_cast<const float4*>(src + (size_t)f * TT);
        // sign of the t+4 element: first element of the next lane's float4
        float nxt = __shfl_down(v.x, 1, 64);
        if (lane == 63) {
            nxt = tail ? 0.0f : src[(size_t)f * TT + 4];
        }
        const int s0 = sgn_bit(v.x), s1 = sgn_bit(v.y), s2 = sgn_bit(v.z),
                  s3 = sgn_bit(v.w), s4 = sgn_bit(nxt);
        a.x = s1 - s0;
        a.y = s2 - s1;
        a.z = s3 - s2;
        a.w = tail ? 0 : (s4 - s3);   // jnp.pad: adj at t = TT-1 is 0
    };

    // ---- prologue: rows fs-1 (halo) and fs ----
    if (fs == 0) {
        aprev = make_int4(9, 9, 9, 9);                 // sentinel: never matches +1
        vprev = make_float4(0.f, 0.f, 0.f, 0.f);
    } else {
        load_row(fs - 1, vprev, aprev);
    }
    load_row(fs, vcur, acur);

    #pragma unroll 4
    for (int g = fs; g < fs + F_CHUNK; ++g) {
        if (g + 1 < FF) {
            load_row(g + 1, vnext, anext);
        } else {
            anext = make_int4(9, 9, 9, 9);             // sentinel: never matches -1
            vnext = make_float4(0.f, 0.f, 0.f, 0.f);
        }

        const bool isFirst = (g == 0);
        const bool isLast  = (g == FF - 1);

        float4 r;
        {
            const bool bc = (acur.x == 0) || (isFirst && acur.x < 0) || (isLast && acur.x > 0);
            r.x = ((aprev.x == 1) ? vprev.x : 0.f) + (bc ? vcur.x : 0.f)
                + ((anext.x == -1) ? vnext.x : 0.f);
        }
        {
            const bool bc = (acur.y == 0) || (isFirst && acur.y < 0) || (isLast && acur.y > 0);
            r.y = ((aprev.y == 1) ? vprev.y : 0.f) + (bc ? vcur.y : 0.f)
                + ((anext.y == -1) ? vnext.y : 0.f);
        }
        {
            const bool bc = (acur.z == 0) || (isFirst && acur.z < 0) || (isLast && acur.z > 0);
            r.z = ((aprev.z == 1) ? vprev.z : 0.f) + (bc ? vcur.z : 0.f)
                + ((anext.z == -1) ? vnext.z : 0.f);
        }
        {
            const bool bc = (acur.w == 0) || (isFirst && acur.w < 0) || (isLast && acur.w > 0);
            r.w = ((aprev.w == 1) ? vprev.w : 0.f) + (bc ? vcur.w : 0.f)
                + ((anext.w == -1) ? vnext.w : 0.f);
        }

        *reinterpret_cast<float4*>(dst + (size_t)g * TT) = r;

        vprev = vcur; aprev = acur;
        vcur  = vnext; acur  = anext;
    }
}

extern "C" void kernel_launch(void* const* d_in, const int* in_sizes, int n_in,
                              void* d_out, int out_size, void* d_ws, size_t ws_size,
                              hipStream_t stream) {
    const float* in  = (const float*)d_in[0];
    float*       out = (float*)d_out;
    // grid: (t-blocks, f-chunks, batch) = (8, 4, 16) -> 512 blocks
    dim3 grid(TT / (THREADS * 4), FF / F_CHUNK, BB);
    sst_kernel<<<grid, THREADS, 0, stream>>>(in, out);
}

// Round 2
// 240.910 us; speedup vs baseline: 1.1309x; 1.1309x over previous
//
#include <hip/hip_runtime.h>

#define BB 16
#define FF 256
#define TT 8192
#define F_CHUNK 16
#define THREADS 256

__device__ __forceinline__ int sgn_bit(float x) {
    return (int)(__float_as_uint(x) >> 31);
}

struct Raw { float4 v; float e; };

__global__ __launch_bounds__(THREADS) void sst_kernel(const float* __restrict__ in,
                                                      float* __restrict__ out) {
    const int t    = blockIdx.x * (THREADS * 4) + threadIdx.x * 4;
    const int fs   = blockIdx.y * F_CHUNK;
    const int b    = blockIdx.z;
    const int lane = threadIdx.x & 63;

    const float* src = in  + (size_t)b * FF * TT + t;
    float*       dst = out + (size_t)b * FF * TT + t;

    // true only for the thread whose last element is t+3 == TT-1 (always lane 63)
    const bool tail = (t + 4 >= TT);

    // Raw load: the float4 plus lane-63's cross-wave neighbor scalar,
    // issued early so neither sits on the critical path.
    auto load_raw = [&](int f) {
        Raw r;
        r.v = *reinterpret_cast<const float4*>(src + (size_t)f * TT);
        r.e = (lane == 63 && !tail) ? src[(size_t)f * TT + 4] : 0.0f;
        return r;
    };
    // Finish: compute the per-element frequency adjustment codes.
    auto adj_of = [&](const Raw& r) {
        float nxt = __shfl_down(r.v.x, 1, 64);
        if (lane == 63) nxt = r.e;  // r.e == 0 when tail; a.w forced 0 anyway
        const int s0 = sgn_bit(r.v.x), s1 = sgn_bit(r.v.y), s2 = sgn_bit(r.v.z),
                  s3 = sgn_bit(r.v.w), s4 = sgn_bit(nxt);
        int4 a;
        a.x = s1 - s0;
        a.y = s2 - s1;
        a.z = s3 - s2;
        a.w = tail ? 0 : (s4 - s3);   // jnp.pad: adj at t = TT-1 is 0
        return a;
    };

    float4 vprev, vcur, vnext;
    int4   aprev, acur, anext;
    Raw    rn, rn2;

    // ---- prologue: rows fs-1 (halo), fs, and raw-load fs+1 ----
    if (fs == 0) {
        aprev = make_int4(9, 9, 9, 9);                 // sentinel: never matches +1
        vprev = make_float4(0.f, 0.f, 0.f, 0.f);
    } else {
        Raw r = load_raw(fs - 1);
        vprev = r.v; aprev = adj_of(r);
    }
    {
        Raw r = load_raw(fs);
        vcur = r.v; acur = adj_of(r);
    }
    rn = load_raw(fs + 1);   // fs+1 <= FF-1 always (fs <= FF - F_CHUNK)

    #pragma unroll
    for (int i = 0; i < F_CHUNK; ++i) {
        const int g = fs + i;

        // prefetch row g+2 (only if it will actually be consumed)
        const bool want2 = (i + 2 <= F_CHUNK) && (g + 2 < FF);
        if (want2) rn2 = load_raw(g + 2);

        // finish row g+1
        if (g + 1 < FF) {
            vnext = rn.v; anext = adj_of(rn);
        } else {
            anext = make_int4(9, 9, 9, 9);             // sentinel: never matches -1
            vnext = make_float4(0.f, 0.f, 0.f, 0.f);
        }

        const bool isFirst = (g == 0);
        const bool isLast  = (g == FF - 1);

        float4 r;
        {
            const bool bc = (acur.x == 0) || (isFirst && acur.x < 0) || (isLast && acur.x > 0);
            r.x = ((aprev.x == 1) ? vprev.x : 0.f) + (bc ? vcur.x : 0.f)
                + ((anext.x == -1) ? vnext.x : 0.f);
        }
        {
            const bool bc = (acur.y == 0) || (isFirst && acur.y < 0) || (isLast && acur.y > 0);
            r.y = ((aprev.y == 1) ? vprev.y : 0.f) + (bc ? vcur.y : 0.f)
                + ((anext.y == -1) ? vnext.y : 0.f);
        }
        {
            const bool bc = (acur.z == 0) || (isFirst && acur.z < 0) || (isLast && acur.z > 0);
            r.z = ((aprev.z == 1) ? vprev.z : 0.f) + (bc ? vcur.z : 0.f)
                + ((anext.z == -1) ? vnext.z : 0.f);
        }
        {
            const bool bc = (acur.w == 0) || (isFirst && acur.w < 0) || (isLast && acur.w > 0);
            r.w = ((aprev.w == 1) ? vprev.w : 0.f) + (bc ? vcur.w : 0.f)
                + ((anext.w == -1) ? vnext.w : 0.f);
        }

        *reinterpret_cast<float4*>(dst + (size_t)g * TT) = r;

        vprev = vcur;  aprev = acur;
        vcur  = vnext; acur  = anext;
        rn    = rn2;
    }
}

extern "C" void kernel_launch(void* const* d_in, const int* in_sizes, int n_in,
                              void* d_out, int out_size, void* d_ws, size_t ws_size,
                              hipStream_t stream) {
    const float* in  = (const float*)d_in[0];
    float*       out = (float*)d_out;
    // grid: (t-blocks, f-chunks, batch) = (8, 16, 16) -> 2048 blocks (8 blocks/CU)
    dim3 grid(TT / (THREADS * 4), FF / F_CHUNK, BB);
    sst_kernel<<<grid, THREADS, 0, stream>>>(in, out);
}